// Round 5
// baseline (418.427 us; speedup 1.0000x reference)
//
#include <hip/hip_runtime.h>
#include <math.h>

typedef unsigned short u16;
using bf16x8 = __attribute__((ext_vector_type(8))) short;
using f32x4  = __attribute__((ext_vector_type(4))) float;

#define NS      128
#define NBLOCKS 4096    // 1 ray per block, 512 threads (8 waves)
#define KS1     15      // 30 channels * 16 slots = 480 K (W1 slices)
#define NSLICE  19      // 15 (W1) + 4 (W2) unified W slices of 4096 u16

// LDS pool (u16 units): X double-buffer = 2 groups x 2 slices x 4096 u16
// (32 KB), fully overlaid by h [128x128] bf16 after GEMM1. W is never
// staged: B-frags stream from L2-resident ws straight into registers.
#define POOLSZ 16384

// Raw barrier: drain LDS only; global register-prefetches stay in flight.
#define BAR() do { asm volatile("s_waitcnt lgkmcnt(0)" ::: "memory");        \
                   __builtin_amdgcn_s_barrier();                              \
                   asm volatile("" ::: "memory"); } while (0)

#define MF(A,B,C) __builtin_amdgcn_mfma_f32_16x16x32_bf16((A),(B),(C),0,0,0)

__device__ __forceinline__ u16 f2bf(float f) {           // host-prep path only
    unsigned int i = __float_as_uint(f);
    return (u16)((i + 0x7FFFu + ((i >> 16) & 1u)) >> 16);  // RNE
}

// pack two floats to bf16 pair [hi:lo] in one dword (single VALU op, RNE)
__device__ __forceinline__ unsigned pk(float hi, float lo) {
    unsigned r;
    asm("v_cvt_pk_bf16_f32 %0, %1, %2" : "=v"(r) : "v"(lo), "v"(hi));
    return r;
}
__device__ __forceinline__ u16 f2bf1(float f) {
    return (u16)((__float_as_uint(f) + 0x8000u) >> 16);
}

// Swizzled A-frag-order offset for the h [128x128] region: XOR (k>>3)&3 into
// the chunk index (readers apply chunk^quad) to spread the epilogue's
// column-wise u16 writes across more banks.
__device__ __forceinline__ int afoff_h(int m, int k) {
    int chunk = ((k >> 5) * 8 + (m >> 4)) * 64 + ((k >> 3) & 3) * 16 + (m & 15);
    chunk ^= (k >> 3) & 3;
    return chunk * 8 + (k & 7);
}

// channel/slot -> original mlp_in k index (reference ordering)
__device__ __forceinline__ int orig_k(int ch, int slot) {
    if (ch < 27) {
        if (slot == 0) return ch;
        if (slot <= 6) return 30 + ch * 6 + (slot - 1);     // sin(app)
        return 192 + ch * 6 + (slot - 7);                    // cos(app)
    } else {
        int c = ch - 27;
        if (slot == 0) return 27 + c;
        if (slot <= 6) return 354 + c * 6 + (slot - 1);      // sin(view)
        return 372 + c * 6 + (slot - 7);                     // cos(view)
    }
}

__device__ __forceinline__ float ldch(const float* ap, const float* vp, int c) {
    return (c < 27) ? ap[c] : vp[c - 27];
}

// build one channel-half of a frag-order X slice at a precomputed dst
// (dst = slice base + per-thread offset, hoisted): slots
// [v, sin f0..5, cos f0..5, 0 x3] as two 16B chunks (dst, dst+128).
__device__ __forceinline__ void build_x(u16* dst, float v) {
    float rev = v * 0.15915494309189535f;
    rev -= floorf(rev);
    float s0 = __builtin_amdgcn_sinf(rev);
    float c0 = __builtin_amdgcn_cosf(rev);
    float s1 = 2.f * s0 * c0, c1 = c0 * c0 - s0 * s0;
    float s2 = 2.f * s1 * c1, c2 = c1 * c1 - s1 * s1;
    float s3 = 2.f * s2 * c2, c3 = c2 * c2 - s2 * s2;
    float s4 = 2.f * s3 * c3, c4 = c3 * c3 - s3 * s3;
    float s5 = 2.f * s4 * c4, c5 = c4 * c4 - s4 * s4;
    uint4 lo, hi;
    lo.x = pk(s0, v);  lo.y = pk(s2, s1);  lo.z = pk(s4, s3);  lo.w = pk(c0, s5);
    hi.x = pk(c2, c1); hi.y = pk(c4, c3);  hi.z = pk(0.f, c5); hi.w = 0u;
    *(uint4*)(dst)       = lo;
    *(uint4*)(dst + 128) = hi;
}

// W1 -> 15 slices, W2 -> 4 slices, W3 -> 4 mini B-frag slices (N padded 16)
__global__ __launch_bounds__(256) void prep_kernel(
    const float* __restrict__ W1, const float* __restrict__ W2,
    const float* __restrict__ W3, u16* __restrict__ ws)
{
    int idx = blockIdx.x * 256 + threadIdx.x;
    if (idx < 61440) {                               // W1r: [ks15][nt8][lane64][j8]
        int j = idx & 7, lane = (idx >> 3) & 63, nt = (idx >> 9) & 7, ks = idx >> 12;
        int q = lane >> 4, l15 = lane & 15;
        int klocal = q * 8 + j;                      // 0..31
        int ch = ks * 2 + (klocal >> 4);
        int slot = klocal & 15;
        int n = nt * 16 + l15;
        ws[idx] = (slot < 13) ? f2bf(W1[orig_k(ch, slot) * 128 + n]) : (u16)0;
    } else if (idx < 77824) {                        // W2r: [ks4][nt8][lane64][j8]
        int i2 = idx - 61440;
        int j = i2 & 7, lane = (i2 >> 3) & 63, nt = (i2 >> 9) & 7, ks = i2 >> 12;
        int k = ks * 32 + (lane >> 4) * 8 + j;
        int n = nt * 16 + (lane & 15);
        ws[idx] = f2bf(W2[k * 128 + n]);
    } else if (idx < 79872) {                        // W3r: [ks4][lane64][j8], N pad 16
        int i3 = idx - 77824;
        int j = i3 & 7, lane = (i3 >> 3) & 63, ks = i3 >> 9;
        int k = ks * 32 + (lane >> 4) * 8 + j;
        int n = lane & 15;
        ws[idx] = (n < 3) ? f2bf(W3[k * 3 + n]) : (u16)0;
    }
}

// Load one slice's 2 B-frags (wave's 32-col strip) into named registers.
#define LOADB2(N0, N1, s)                                                     \
    if ((s) < NSLICE) {                                                       \
        const u16* wp = wp0 + (s) * 4096;                                     \
        N0 = *(const bf16x8*)(wp);                                            \
        N1 = *(const bf16x8*)(wp + 512);                                      \
    }

// One X-sourced K-slice: 4 A ds_reads (64-row strip, split 2+2 to cap reg
// pressure) + 8 MFMA. Loads slice s+2's B-frags (3-pair rotation P,Q,R).
#define BODYX(s, C0,C1, N0,N1)                                                \
  {                                                                           \
    LOADB2(N0, N1, (s)+2);                                                    \
    const u16* ab = pool + ((((s)>>1)&1) ? 8192 : 0) + (((s)&1)*4096)         \
                    + (wm*256 + lane)*8;                                      \
    bf16x8 a0 = *(const bf16x8*)(ab);                                         \
    bf16x8 a1 = *(const bf16x8*)(ab + 512);                                   \
    __builtin_amdgcn_s_setprio(1);                                            \
    acc[0][0]=MF(a0,C0,acc[0][0]); acc[0][1]=MF(a0,C1,acc[0][1]);             \
    acc[1][0]=MF(a1,C0,acc[1][0]); acc[1][1]=MF(a1,C1,acc[1][1]);             \
    a0 = *(const bf16x8*)(ab + 1024);                                         \
    a1 = *(const bf16x8*)(ab + 1536);                                         \
    acc[2][0]=MF(a0,C0,acc[2][0]); acc[2][1]=MF(a0,C1,acc[2][1]);             \
    acc[3][0]=MF(a1,C0,acc[3][0]); acc[3][1]=MF(a1,C1,acc[3][1]);             \
    __builtin_amdgcn_s_setprio(0);                                            \
  }

// One h-sourced K-slice (GEMM2): A from swizzled h chunks.
#define BODYH(s, C0,C1, N0,N1)                                                \
  {                                                                           \
    LOADB2(N0, N1, (s)+2);                                                    \
    int cb = ((((s)-15)*512) + wm*256 + lane) ^ quad;                         \
    bf16x8 a0 = *(const bf16x8*)(pool + cb*8);                                \
    bf16x8 a1 = *(const bf16x8*)(pool + (cb+64)*8);                           \
    __builtin_amdgcn_s_setprio(1);                                            \
    acc[0][0]=MF(a0,C0,acc[0][0]); acc[0][1]=MF(a0,C1,acc[0][1]);             \
    acc[1][0]=MF(a1,C0,acc[1][0]); acc[1][1]=MF(a1,C1,acc[1][1]);             \
    a0 = *(const bf16x8*)(pool + (cb+128)*8);                                 \
    a1 = *(const bf16x8*)(pool + (cb+192)*8);                                 \
    acc[2][0]=MF(a0,C0,acc[2][0]); acc[2][1]=MF(a0,C1,acc[2][1]);             \
    acc[3][0]=MF(a1,C0,acc[3][0]); acc[3][1]=MF(a1,C1,acc[3][1]);             \
    __builtin_amdgcn_s_setprio(0);                                            \
  }

// End of group g (slices 2g,2g+1): build group g+1's X slices, roll the
// 2-deep input prefetch (load group g+3), barrier.
#define GEND(g)                                                               \
  {                                                                           \
    if (4*((g)+1) + cl < 30)                                                  \
        build_x(pool + ((((g)+1)&1) ? 8192 : 0) + (cl>>1)*4096 + bxoff,       \
                pv_cur);                                                      \
    pv_cur = pv_nxt;                                                          \
    if (4*((g)+3) + cl < 30) pv_nxt = ldch(ap, vp, 4*((g)+3) + cl);           \
    BAR();                                                                    \
  }

// 8 waves: wave (wm = wave>>2, wn = wave&3) owns a 64x32 output tile
// (A-amp 4 via LDS, B-amp 2 via L1/L2 -- the round-3 shape).
// (512,6): cap alloc at 85 unified regs -> 3 blocks/CU (24 waves).
__global__ __launch_bounds__(512, 6) void render_kernel(
    const float* __restrict__ sigma_g, const float* __restrict__ app_g,
    const float* __restrict__ view_g,  const float* __restrict__ dists_g,
    const float* __restrict__ b1_g,    const float* __restrict__ b2_g,
    const float* __restrict__ b3_g,    const u16* __restrict__ ws,
    float* __restrict__ out_g)
{
    __shared__ __align__(16) u16 pool[POOLSZ];
    __shared__ __align__(16) float part[NS * 3];
    __shared__ float scanS;          // wave0 scan total broadcast
    __shared__ float sum2[6];        // per-wave final partials

    const int tid  = threadIdx.x;
    const int lane = tid & 63;
    const int wave = tid >> 6;       // 0..7
    const int l15  = lane & 15;
    const int quad = lane >> 4;
    const int wm   = wave >> 2;      // row half (64 rows)
    const int wn   = wave & 3;       // col quarter (32 cols)

    const int r  = blockIdx.x;
    const int rb = r * NS;
    const int row = tid & 127;       // X-build row (all 512 threads build)
    const int cl  = tid >> 7;        // X-build channel-local 0..3 (2 slices)
    const float* ap = app_g  + (rb + row) * 27;
    const float* vp = view_g + (rb + row) * 3;
    // hoisted per-thread build offset within a slice
    const int bxoff = (row >> 4) * 512 + (((cl & 1) * 32) + (row & 15)) * 8;

    // issue B loads for slices 0,1 ASAP (3-pair rotation P,Q,R)
    const u16* wp0 = ws + (wn * 128 + lane) * 8;
    bf16x8 bP0, bP1, bQ0, bQ1, bR0, bR1;
    LOADB2(bP0, bP1, 0);
    LOADB2(bQ0, bQ1, 1);

    // rolling input prefetch (2 resident)
    float pv_cur = ldch(ap, vp, cl);             // group 0
    float pv_nxt = ldch(ap, vp, 4 + cl);         // group 1

    // ---- alpha + shuffle transmittance scan (waves 0,1) ----
    float alpha = 0.f, prod = 1.f, wr = 0.f;
    if (tid < NS) {
        float x  = sigma_g[rb + tid] - 10.f;
        float sp = (x > 20.f) ? x : log1pf(expf(x));
        alpha = 1.f - expf(-sp * dists_g[rb + tid] * 25.f);
        if (tid == NS - 1) alpha = 1.f;
        float tb = 1.f - alpha + 1e-10f;
        prod = tb;
        #pragma unroll
        for (int d = 1; d < 64; d <<= 1) {
            float v = __shfl_up(prod, d);
            if (lane >= d) prod *= v;
        }
        if (tid == 63) scanS = prod;
    }

    // ---- build X group 0 (slices 0,1; channels 0..3) into buf0 ----
    build_x(pool + (cl >> 1) * 4096 + bxoff, pv_cur);
    pv_cur = pv_nxt;
    pv_nxt = ldch(ap, vp, 8 + cl);               // group 2
    BAR();

    // finish weights: wr = alpha * T_exclusive
    if (tid < NS) {
        float prev = __shfl_up(prod, 1);
        float base = (lane == 0) ? 1.f : prev;
        float scale = (wave == 1) ? scanS : 1.f;
        wr = alpha * base * scale;
    }

    const f32x4 vzero = {0.f, 0.f, 0.f, 0.f};
    f32x4 acc[4][2];
    #pragma unroll
    for (int mt = 0; mt < 4; ++mt)
        #pragma unroll
        for (int nt = 0; nt < 2; ++nt) acc[mt][nt] = vzero;

    // ---- GEMM1: slices 0..14 (pair s%3: 0=P 1=Q 2=R) ----
    BODYX(0,  bP0,bP1, bR0,bR1);
    BODYX(1,  bQ0,bQ1, bP0,bP1);  GEND(0);
    BODYX(2,  bR0,bR1, bQ0,bQ1);
    BODYX(3,  bP0,bP1, bR0,bR1);  GEND(1);
    BODYX(4,  bQ0,bQ1, bP0,bP1);
    BODYX(5,  bR0,bR1, bQ0,bQ1);  GEND(2);
    BODYX(6,  bP0,bP1, bR0,bR1);
    BODYX(7,  bQ0,bQ1, bP0,bP1);  GEND(3);
    BODYX(8,  bR0,bR1, bQ0,bQ1);
    BODYX(9,  bP0,bP1, bR0,bR1);  GEND(4);
    BODYX(10, bQ0,bQ1, bP0,bP1);
    BODYX(11, bR0,bR1, bQ0,bQ1);  GEND(5);
    BODYX(12, bP0,bP1, bR0,bR1);
    BODYX(13, bQ0,bQ1, bP0,bP1);  GEND(6);   // loads slice 15 -> P
    BODYX(14, bR0,bR1, bQ0,bQ1);             // loads slice 16 -> Q
    // b1 loads issued before the barrier; they fly across it (no vm drain)
    const float b1r0 = b1_g[wn * 32 + l15];
    const float b1r1 = b1_g[wn * 32 + 16 + l15];
    BAR();   // all slice-14 A-reads done before h1 overwrites X

    // ---- epilogue 1: h1 = relu(acc + b1) -> pool (bf16, swizzled order) ----
    #pragma unroll
    for (int mt = 0; mt < 4; ++mt)
        #pragma unroll
        for (int nt = 0; nt < 2; ++nt) {
            int col = wn * 32 + nt * 16 + l15;
            #pragma unroll
            for (int rr = 0; rr < 4; ++rr) {
                int rw = wm * 64 + mt * 16 + quad * 4 + rr;
                pool[afoff_h(rw, col)] =
                    f2bf1(fmaxf(acc[mt][nt][rr] + ((nt == 0) ? b1r0 : b1r1), 0.f));
            }
            acc[mt][nt] = vzero;          // reset for GEMM2
        }
    BAR();   // h1 visible to all waves

    // ---- GEMM2: slices 15..18 (h1 @ W2), barrier-free run ----
    BODYH(15, bP0,bP1, bR0,bR1);             // loads slice 17 -> R
    BODYH(16, bQ0,bQ1, bP0,bP1);             // loads slice 18 -> P
    BODYH(17, bR0,bR1, bQ0,bQ1);
    BODYH(18, bP0,bP1, bR0,bR1);
    BAR();   // all GEMM2 h1-reads done before h2 overwrites

    // ---- epilogue 2: h2 = relu(acc + b2) -> overlays h1 ----
    const float b2r0 = b2_g[wn * 32 + l15];
    const float b2r1 = b2_g[wn * 32 + 16 + l15];
    #pragma unroll
    for (int mt = 0; mt < 4; ++mt)
        #pragma unroll
        for (int nt = 0; nt < 2; ++nt) {
            int col = wn * 32 + nt * 16 + l15;
            #pragma unroll
            for (int rr = 0; rr < 4; ++rr) {
                int rw = wm * 64 + mt * 16 + quad * 4 + rr;
                pool[afoff_h(rw, col)] =
                    f2bf1(fmaxf(acc[mt][nt][rr] + ((nt == 0) ? b2r0 : b2r1), 0.f));
            }
        }
    BAR();

    // ---- layer 3 via MFMA: rgb = sigmoid(h2 @ W3 + b3); wave = row-tile ----
    const u16* w3r = ws + 77824;
    const float b3v = (l15 < 3) ? b3_g[l15] : 0.f;
    f32x4 acc3 = vzero;
    #pragma unroll
    for (int ks = 0; ks < 4; ++ks) {
        bf16x8 w3f = *(const bf16x8*)(w3r + (ks * 64 + lane) * 8);
        int c = ((ks * 8 + wave) * 64 + lane) ^ quad;
        bf16x8 a3 = *(const bf16x8*)(pool + c * 8);
        acc3 = MF(a3, w3f, acc3);
    }
    if (l15 < 3) {
        #pragma unroll
        for (int rr = 0; rr < 4; ++rr) {
            int rw = wave * 16 + quad * 4 + rr;
            float v = acc3[rr] + b3v;
            part[rw * 3 + l15] = 1.f / (1.f + expf(-v));
        }
    }
    BAR();

    // ---- weighted sum over samples ----
    if (tid < NS) {
        float v0 = wr * part[tid * 3 + 0];
        float v1 = wr * part[tid * 3 + 1];
        float v2 = wr * part[tid * 3 + 2];
        #pragma unroll
        for (int d = 1; d < 64; d <<= 1) {
            v0 += __shfl_xor(v0, d);
            v1 += __shfl_xor(v1, d);
            v2 += __shfl_xor(v2, d);
        }
        if (lane == 0) {
            sum2[wave * 3 + 0] = v0;
            sum2[wave * 3 + 1] = v1;
            sum2[wave * 3 + 2] = v2;
        }
    }
    BAR();
    if (tid == 0) {
        out_g[r * 3 + 0] = sum2[0] + sum2[3];
        out_g[r * 3 + 1] = sum2[1] + sum2[4];
        out_g[r * 3 + 2] = sum2[2] + sum2[5];
    }
}

extern "C" void kernel_launch(void* const* d_in, const int* in_sizes, int n_in,
                              void* d_out, int out_size, void* d_ws, size_t ws_size,
                              hipStream_t stream) {
    (void)in_sizes; (void)n_in; (void)out_size; (void)ws_size;
    const float* sigma = (const float*)d_in[0];
    const float* app   = (const float*)d_in[1];
    const float* view  = (const float*)d_in[2];
    const float* dists = (const float*)d_in[3];
    const float* W1    = (const float*)d_in[4];
    const float* b1    = (const float*)d_in[5];
    const float* W2    = (const float*)d_in[6];
    const float* b2    = (const float*)d_in[7];
    const float* W3    = (const float*)d_in[8];
    const float* b3    = (const float*)d_in[9];
    float* out = (float*)d_out;

    u16* ws = (u16*)d_ws;   // 61440 (W1r) + 16384 (W2r) + 2048 (W3r) u16 = 159744 B

    prep_kernel<<<312, 256, 0, stream>>>(W1, W2, W3, ws);
    render_kernel<<<NBLOCKS, 512, 0, stream>>>(sigma, app, view, dists,
                                               b1, b2, b3, ws, out);
}

// Round 6
// 248.788 us; speedup vs baseline: 1.6819x; 1.6819x over previous
//
#include <hip/hip_runtime.h>
#include <math.h>

typedef unsigned short u16;
using bf16x8 = __attribute__((ext_vector_type(8))) short;
using f32x4  = __attribute__((ext_vector_type(4))) float;

#define NS      128
#define NBLOCKS 8192    // 2 blocks per ray (64 samples each), 256 threads
#define KS1     15      // 30 channels * 16 slots = 480 K (W1 slices)
#define NSLICE  19      // 15 (W1) + 4 (W2) unified W slices of 4096 u16

// LDS pool (u16 units): X double-buffer = 2 groups x 2 slices x 2048 u16
// (16 KB, 64-row slices), exactly overlaid by h [64x128] bf16 after GEMM1.
// W is never staged: B-frags stream from L2-resident ws into registers.
#define POOLSZ 8192

// Raw barrier: drain LDS only; global register-prefetches stay in flight.
#define BAR() do { asm volatile("s_waitcnt lgkmcnt(0)" ::: "memory");        \
                   __builtin_amdgcn_s_barrier();                              \
                   asm volatile("" ::: "memory"); } while (0)

#define MF(A,B,C) __builtin_amdgcn_mfma_f32_16x16x32_bf16((A),(B),(C),0,0,0)

__device__ __forceinline__ u16 f2bf(float f) {           // host-prep path only
    unsigned int i = __float_as_uint(f);
    return (u16)((i + 0x7FFFu + ((i >> 16) & 1u)) >> 16);  // RNE
}

// pack two floats to bf16 pair [hi:lo] in one dword (single VALU op, RNE)
__device__ __forceinline__ unsigned pk(float hi, float lo) {
    unsigned r;
    asm("v_cvt_pk_bf16_f32 %0, %1, %2" : "=v"(r) : "v"(lo), "v"(hi));
    return r;
}
__device__ __forceinline__ u16 f2bf1(float f) {
    return (u16)((__float_as_uint(f) + 0x8000u) >> 16);
}

// Swizzled A-frag-order offset into the h [64x128] region (4 k-slices of
// 2048 u16): XOR (k>>3)&3 into the within-slice chunk index (readers apply
// chunk^quad) to spread the epilogue's column-wise u16 writes across banks.
__device__ __forceinline__ int afoff_h(int m, int k) {
    int chunk = (m >> 4) * 64 + ((k >> 3) & 3) * 16 + (m & 15);
    chunk ^= (k >> 3) & 3;
    return (k >> 5) * 2048 + chunk * 8 + (k & 7);
}

// channel/slot -> original mlp_in k index (reference ordering)
__device__ __forceinline__ int orig_k(int ch, int slot) {
    if (ch < 27) {
        if (slot == 0) return ch;
        if (slot <= 6) return 30 + ch * 6 + (slot - 1);     // sin(app)
        return 192 + ch * 6 + (slot - 7);                    // cos(app)
    } else {
        int c = ch - 27;
        if (slot == 0) return 27 + c;
        if (slot <= 6) return 354 + c * 6 + (slot - 1);      // sin(view)
        return 372 + c * 6 + (slot - 7);                     // cos(view)
    }
}

__device__ __forceinline__ float ldch(const float* ap, const float* vp, int c) {
    return (c < 27) ? ap[c] : vp[c - 27];
}

// build one channel-half of a frag-order X slice at a precomputed dst:
// slots [v, sin f0..5, cos f0..5, 0 x3] as two 16B chunks (dst, dst+128).
__device__ __forceinline__ void build_x(u16* dst, float v) {
    float rev = v * 0.15915494309189535f;
    rev -= floorf(rev);
    float s0 = __builtin_amdgcn_sinf(rev);
    float c0 = __builtin_amdgcn_cosf(rev);
    float s1 = 2.f * s0 * c0, c1 = c0 * c0 - s0 * s0;
    float s2 = 2.f * s1 * c1, c2 = c1 * c1 - s1 * s1;
    float s3 = 2.f * s2 * c2, c3 = c2 * c2 - s2 * s2;
    float s4 = 2.f * s3 * c3, c4 = c3 * c3 - s3 * s3;
    float s5 = 2.f * s4 * c4, c5 = c4 * c4 - s4 * s4;
    uint4 lo, hi;
    lo.x = pk(s0, v);  lo.y = pk(s2, s1);  lo.z = pk(s4, s3);  lo.w = pk(c0, s5);
    hi.x = pk(c2, c1); hi.y = pk(c4, c3);  hi.z = pk(0.f, c5); hi.w = 0u;
    *(uint4*)(dst)       = lo;
    *(uint4*)(dst + 128) = hi;
}

// W1 -> 15 slices, W2 -> 4 slices, W3 -> 4 mini B-frag slices (N padded 16);
// also zeroes the output (render halves atomicAdd into it).
__global__ __launch_bounds__(256) void prep_kernel(
    const float* __restrict__ W1, const float* __restrict__ W2,
    const float* __restrict__ W3, u16* __restrict__ ws,
    float* __restrict__ out)
{
    int idx = blockIdx.x * 256 + threadIdx.x;
    if (idx < 12288) out[idx] = 0.f;                 // 4096 rays x 3
    if (idx < 61440) {                               // W1r: [ks15][nt8][lane64][j8]
        int j = idx & 7, lane = (idx >> 3) & 63, nt = (idx >> 9) & 7, ks = idx >> 12;
        int q = lane >> 4, l15 = lane & 15;
        int klocal = q * 8 + j;                      // 0..31
        int ch = ks * 2 + (klocal >> 4);
        int slot = klocal & 15;
        int n = nt * 16 + l15;
        ws[idx] = (slot < 13) ? f2bf(W1[orig_k(ch, slot) * 128 + n]) : (u16)0;
    } else if (idx < 77824) {                        // W2r: [ks4][nt8][lane64][j8]
        int i2 = idx - 61440;
        int j = i2 & 7, lane = (i2 >> 3) & 63, nt = (i2 >> 9) & 7, ks = i2 >> 12;
        int k = ks * 32 + (lane >> 4) * 8 + j;
        int n = nt * 16 + (lane & 15);
        ws[idx] = f2bf(W2[k * 128 + n]);
    } else if (idx < 79872) {                        // W3r: [ks4][lane64][j8], N pad 16
        int i3 = idx - 77824;
        int j = i3 & 7, lane = (i3 >> 3) & 63, ks = i3 >> 9;
        int k = ks * 32 + (lane >> 4) * 8 + j;
        int n = lane & 15;
        ws[idx] = (n < 3) ? f2bf(W3[k * 3 + n]) : (u16)0;
    }
}

// Load one slice's 4 B-frags (wave's 64-col strip) into named registers.
#define LOADB4(N0,N1,N2,N3, s)                                                \
    if ((s) < NSLICE) {                                                       \
        const u16* wp = wp0 + (s) * 4096;                                     \
        N0 = *(const bf16x8*)(wp);                                            \
        N1 = *(const bf16x8*)(wp + 512);                                      \
        N2 = *(const bf16x8*)(wp + 1024);                                     \
        N3 = *(const bf16x8*)(wp + 1536);                                     \
    }

// One X-sourced K-slice: 2 A ds_reads (32-row wave strip) + 8 MFMA.
// Loads slice s+1's B-frags (2-deep ping-pong).
#define BODYX(s, C0,C1,C2,C3, N0,N1,N2,N3)                                    \
  {                                                                           \
    LOADB4(N0,N1,N2,N3, (s)+1);                                               \
    const u16* ab = pool + ((((s)>>1)&1) ? 4096 : 0) + (((s)&1)*2048)         \
                    + (wm*128 + lane)*8;                                      \
    bf16x8 a0 = *(const bf16x8*)(ab);                                         \
    bf16x8 a1 = *(const bf16x8*)(ab + 512);                                   \
    __builtin_amdgcn_s_setprio(1);                                            \
    acc[0][0]=MF(a0,C0,acc[0][0]); acc[0][1]=MF(a0,C1,acc[0][1]);             \
    acc[0][2]=MF(a0,C2,acc[0][2]); acc[0][3]=MF(a0,C3,acc[0][3]);             \
    acc[1][0]=MF(a1,C0,acc[1][0]); acc[1][1]=MF(a1,C1,acc[1][1]);             \
    acc[1][2]=MF(a1,C2,acc[1][2]); acc[1][3]=MF(a1,C3,acc[1][3]);             \
    __builtin_amdgcn_s_setprio(0);                                            \
  }

// One h-sourced K-slice (GEMM2): A from swizzled h chunks.
#define BODYH(s, C0,C1,C2,C3, N0,N1,N2,N3)                                    \
  {                                                                           \
    LOADB4(N0,N1,N2,N3, (s)+1);                                               \
    int cb = (((s)-15)*256);                                                  \
    bf16x8 a0 = *(const bf16x8*)(pool + (cb + ((wm*128 + lane) ^ quad))*8);   \
    bf16x8 a1 = *(const bf16x8*)(pool + (cb + ((wm*128 + 64 + lane) ^ quad))*8);\
    __builtin_amdgcn_s_setprio(1);                                            \
    acc[0][0]=MF(a0,C0,acc[0][0]); acc[0][1]=MF(a0,C1,acc[0][1]);             \
    acc[0][2]=MF(a0,C2,acc[0][2]); acc[0][3]=MF(a0,C3,acc[0][3]);             \
    acc[1][0]=MF(a1,C0,acc[1][0]); acc[1][1]=MF(a1,C1,acc[1][1]);             \
    acc[1][2]=MF(a1,C2,acc[1][2]); acc[1][3]=MF(a1,C3,acc[1][3]);             \
    __builtin_amdgcn_s_setprio(0);                                            \
  }

// End of group g (slices 2g,2g+1): build group g+1's X slices, roll the
// 2-deep input prefetch (load group g+3), barrier.
#define GEND(g)                                                               \
  {                                                                           \
    if (4*((g)+1) + cl < 30)                                                  \
        build_x(pool + ((((g)+1)&1) ? 4096 : 0) + (cl>>1)*2048 + bxoff,       \
                pv_cur);                                                      \
    pv_cur = pv_nxt;                                                          \
    if (4*((g)+3) + cl < 30) pv_nxt = ldch(ap, vp, 4*((g)+3) + cl);           \
    BAR();                                                                    \
  }

// 4 waves: wave (wm = wave>>1, wn = wave&1) owns a 32x64 output tile of the
// block's 64x128 h half-tile. A-amp 2 via LDS, B via L1/L2 registers.
// (256,5): 4-wave blocks -> 5 blocks/CU (20 waves, 62%) at <=102 regs.
__global__ __launch_bounds__(256, 5) void render_kernel(
    const float* __restrict__ sigma_g, const float* __restrict__ app_g,
    const float* __restrict__ view_g,  const float* __restrict__ dists_g,
    const float* __restrict__ b1_g,    const float* __restrict__ b2_g,
    const float* __restrict__ b3_g,    const u16* __restrict__ ws,
    float* __restrict__ out_g)
{
    __shared__ __align__(16) u16 pool[POOLSZ];
    __shared__ __align__(16) float part[64 * 3];
    __shared__ float scanS;          // wave0 scan total broadcast

    const int tid  = threadIdx.x;
    const int lane = tid & 63;
    const int wave = tid >> 6;       // 0..3
    const int l15  = lane & 15;
    const int quad = lane >> 4;
    const int wm   = wave >> 1;      // row half of the 64-row tile (32 rows)
    const int wn   = wave & 1;       // col half (64 cols)

    const int r    = blockIdx.x >> 1;
    const int half = blockIdx.x & 1; // which 64-sample half of the ray
    const int rb   = r * NS;
    const int row  = tid & 63;       // X-build row (local sample)
    const int cl   = tid >> 6;       // X-build channel-local 0..3 (2 slices)
    const float* ap = app_g  + (rb + half * 64 + row) * 27;
    const float* vp = view_g + (rb + half * 64 + row) * 3;
    // hoisted per-thread build offset within a slice
    const int bxoff = (row >> 4) * 512 + (((cl & 1) * 32) + (row & 15)) * 8;

    // issue B loads for slice 0 ASAP (2-deep ping-pong P,Q)
    const u16* wp0 = ws + (wn * 256 + lane) * 8;
    bf16x8 bP0, bP1, bP2, bP3, bQ0, bQ1, bQ2, bQ3;
    LOADB4(bP0, bP1, bP2, bP3, 0);

    // rolling input prefetch (2 resident)
    float pv_cur = ldch(ap, vp, cl);             // group 0
    float pv_nxt = ldch(ap, vp, 4 + cl);         // group 1

    // ---- alpha + shuffle transmittance scan over the FULL ray (waves 0,1) ----
    float alpha = 0.f, prod = 1.f, wr = 0.f;
    if (tid < NS) {
        float x  = sigma_g[rb + tid] - 10.f;
        float sp = (x > 20.f) ? x : log1pf(expf(x));
        alpha = 1.f - expf(-sp * dists_g[rb + tid] * 25.f);
        if (tid == NS - 1) alpha = 1.f;
        float tb = 1.f - alpha + 1e-10f;
        prod = tb;
        #pragma unroll
        for (int d = 1; d < 64; d <<= 1) {
            float v = __shfl_up(prod, d);
            if (lane >= d) prod *= v;
        }
        if (tid == 63) scanS = prod;
    }

    // ---- build X group 0 (slices 0,1; channels 0..3) into buf0 ----
    build_x(pool + (cl >> 1) * 2048 + bxoff, pv_cur);
    pv_cur = pv_nxt;
    pv_nxt = ldch(ap, vp, 8 + cl);               // group 2
    BAR();

    // finish weights: wr = alpha * T_exclusive (global sample = tid)
    if (tid < NS) {
        float prev = __shfl_up(prod, 1);
        float base = (lane == 0) ? 1.f : prev;
        float scale = (wave == 1) ? scanS : 1.f;
        wr = alpha * base * scale;
    }

    const f32x4 vzero = {0.f, 0.f, 0.f, 0.f};
    f32x4 acc[2][4];
    #pragma unroll
    for (int mt = 0; mt < 2; ++mt)
        #pragma unroll
        for (int nt = 0; nt < 4; ++nt) acc[mt][nt] = vzero;

    // ---- GEMM1: slices 0..14 (even uses P, odd uses Q) ----
    BODYX(0,  bP0,bP1,bP2,bP3, bQ0,bQ1,bQ2,bQ3);
    BODYX(1,  bQ0,bQ1,bQ2,bQ3, bP0,bP1,bP2,bP3);  GEND(0);
    BODYX(2,  bP0,bP1,bP2,bP3, bQ0,bQ1,bQ2,bQ3);
    BODYX(3,  bQ0,bQ1,bQ2,bQ3, bP0,bP1,bP2,bP3);  GEND(1);
    BODYX(4,  bP0,bP1,bP2,bP3, bQ0,bQ1,bQ2,bQ3);
    BODYX(5,  bQ0,bQ1,bQ2,bQ3, bP0,bP1,bP2,bP3);  GEND(2);
    BODYX(6,  bP0,bP1,bP2,bP3, bQ0,bQ1,bQ2,bQ3);
    BODYX(7,  bQ0,bQ1,bQ2,bQ3, bP0,bP1,bP2,bP3);  GEND(3);
    BODYX(8,  bP0,bP1,bP2,bP3, bQ0,bQ1,bQ2,bQ3);
    BODYX(9,  bQ0,bQ1,bQ2,bQ3, bP0,bP1,bP2,bP3);  GEND(4);
    BODYX(10, bP0,bP1,bP2,bP3, bQ0,bQ1,bQ2,bQ3);
    BODYX(11, bQ0,bQ1,bQ2,bQ3, bP0,bP1,bP2,bP3);  GEND(5);
    BODYX(12, bP0,bP1,bP2,bP3, bQ0,bQ1,bQ2,bQ3);
    BODYX(13, bQ0,bQ1,bQ2,bQ3, bP0,bP1,bP2,bP3);  GEND(6);   // builds slice 14
    BODYX(14, bP0,bP1,bP2,bP3, bQ0,bQ1,bQ2,bQ3);             // loads slice 15 -> Q
    // b1 loads issued before the barrier; they fly across it (no vm drain)
    float b1r[4];
    #pragma unroll
    for (int nt = 0; nt < 4; ++nt) b1r[nt] = b1_g[wn * 64 + nt * 16 + l15];
    BAR();   // all slice-14 A-reads done before h1 overwrites X

    // ---- epilogue 1: h1 = relu(acc + b1) -> pool (bf16, swizzled order) ----
    #pragma unroll
    for (int mt = 0; mt < 2; ++mt)
        #pragma unroll
        for (int nt = 0; nt < 4; ++nt) {
            int col = wn * 64 + nt * 16 + l15;
            #pragma unroll
            for (int rr = 0; rr < 4; ++rr) {
                int rw = wm * 32 + mt * 16 + quad * 4 + rr;
                pool[afoff_h(rw, col)] =
                    f2bf1(fmaxf(acc[mt][nt][rr] + b1r[nt], 0.f));
            }
            acc[mt][nt] = vzero;          // reset for GEMM2
        }
    BAR();   // h1 visible to all waves

    // ---- GEMM2: slices 15..18 (h1 @ W2), barrier-free run ----
    BODYH(15, bQ0,bQ1,bQ2,bQ3, bP0,bP1,bP2,bP3);             // loads 16 -> P
    BODYH(16, bP0,bP1,bP2,bP3, bQ0,bQ1,bQ2,bQ3);             // loads 17 -> Q
    BODYH(17, bQ0,bQ1,bQ2,bQ3, bP0,bP1,bP2,bP3);             // loads 18 -> P
    BODYH(18, bP0,bP1,bP2,bP3, bQ0,bQ1,bQ2,bQ3);
    BAR();   // all GEMM2 h1-reads done before h2 overwrites

    // ---- epilogue 2: h2 = relu(acc + b2) -> overlays h1 ----
    float b2r[4];
    #pragma unroll
    for (int nt = 0; nt < 4; ++nt) b2r[nt] = b2_g[wn * 64 + nt * 16 + l15];
    #pragma unroll
    for (int mt = 0; mt < 2; ++mt)
        #pragma unroll
        for (int nt = 0; nt < 4; ++nt) {
            int col = wn * 64 + nt * 16 + l15;
            #pragma unroll
            for (int rr = 0; rr < 4; ++rr) {
                int rw = wm * 32 + mt * 16 + quad * 4 + rr;
                pool[afoff_h(rw, col)] =
                    f2bf1(fmaxf(acc[mt][nt][rr] + b2r[nt], 0.f));
            }
        }
    BAR();

    // ---- layer 3 via MFMA: rgb = sigmoid(h2 @ W3 + b3); wave = 16-row tile ----
    const u16* w3r = ws + 77824;
    const float b3v = (l15 < 3) ? b3_g[l15] : 0.f;
    f32x4 acc3 = vzero;
    #pragma unroll
    for (int ks = 0; ks < 4; ++ks) {
        bf16x8 w3f = *(const bf16x8*)(w3r + (ks * 64 + lane) * 8);
        int c = ks * 256 + ((wave * 64 + lane) ^ quad);
        bf16x8 a3 = *(const bf16x8*)(pool + c * 8);
        acc3 = MF(a3, w3f, acc3);
    }
    if (l15 < 3) {
        #pragma unroll
        for (int rr = 0; rr < 4; ++rr) {
            int rw = wave * 16 + quad * 4 + rr;
            float v = acc3[rr] + b3v;
            part[rw * 3 + l15] = 1.f / (1.f + expf(-v));
        }
    }
    BAR();

    // ---- weighted sum over this half's samples; atomicAdd the partial ----
    if ((tid >> 6) == half) {        // exactly wave 'half': tid == global sample
        int local = tid & 63;
        float v0 = wr * part[local * 3 + 0];
        float v1 = wr * part[local * 3 + 1];
        float v2 = wr * part[local * 3 + 2];
        #pragma unroll
        for (int d = 1; d < 64; d <<= 1) {
            v0 += __shfl_xor(v0, d);
            v1 += __shfl_xor(v1, d);
            v2 += __shfl_xor(v2, d);
        }
        if (lane == 0) {
            atomicAdd(&out_g[r * 3 + 0], v0);
            atomicAdd(&out_g[r * 3 + 1], v1);
            atomicAdd(&out_g[r * 3 + 2], v2);
        }
    }
}

extern "C" void kernel_launch(void* const* d_in, const int* in_sizes, int n_in,
                              void* d_out, int out_size, void* d_ws, size_t ws_size,
                              hipStream_t stream) {
    (void)in_sizes; (void)n_in; (void)out_size; (void)ws_size;
    const float* sigma = (const float*)d_in[0];
    const float* app   = (const float*)d_in[1];
    const float* view  = (const float*)d_in[2];
    const float* dists = (const float*)d_in[3];
    const float* W1    = (const float*)d_in[4];
    const float* b1    = (const float*)d_in[5];
    const float* W2    = (const float*)d_in[6];
    const float* b2    = (const float*)d_in[7];
    const float* W3    = (const float*)d_in[8];
    const float* b3    = (const float*)d_in[9];
    float* out = (float*)d_out;

    u16* ws = (u16*)d_ws;   // 61440 (W1r) + 16384 (W2r) + 2048 (W3r) u16 = 159744 B

    prep_kernel<<<312, 256, 0, stream>>>(W1, W2, W3, ws, out);
    render_kernel<<<NBLOCKS, 256, 0, stream>>>(sigma, app, view, dists,
                                               b1, b2, b3, ws, out);
}

// Round 7
// 193.213 us; speedup vs baseline: 2.1656x; 1.2876x over previous
//
#include <hip/hip_runtime.h>
#include <math.h>

typedef unsigned short u16;
using bf16x8 = __attribute__((ext_vector_type(8))) short;
using f32x4  = __attribute__((ext_vector_type(4))) float;

#define NS      128
#define NBLOCKS 4096    // 1 ray per block, 512 threads (8 waves)
#define NSLICE  19      // 15 (W1) + 4 (W2) unified W slices of 4096 u16

// LDS pool (u16): X QUAD-buffer = 4 group slots x 8192 u16 = 64 KB.
// Slice s lives at (s&7)*4096 (identity: slot (s>>1)&3, half s&1).
// h1 overlays slots 0,1 (u16 0..16384); h2 overlays slots 2,3 (16384..32768)
// -> epilogue writes never race live readers, so no read-drain barriers.
#define POOLSZ 32768
#define OH2    16384

// Raw barrier: drain LDS only; global register-prefetches stay in flight.
#define BAR() do { asm volatile("s_waitcnt lgkmcnt(0)" ::: "memory");        \
                   __builtin_amdgcn_s_barrier();                              \
                   asm volatile("" ::: "memory"); } while (0)

#define MF(A,B,C) __builtin_amdgcn_mfma_f32_16x16x32_bf16((A),(B),(C),0,0,0)

__device__ __forceinline__ u16 f2bf(float f) {           // host-prep path only
    unsigned int i = __float_as_uint(f);
    return (u16)((i + 0x7FFFu + ((i >> 16) & 1u)) >> 16);  // RNE
}

// pack two floats to bf16 pair [hi:lo] in one dword (single VALU op, RNE)
__device__ __forceinline__ unsigned pk(float hi, float lo) {
    unsigned r;
    asm("v_cvt_pk_bf16_f32 %0, %1, %2" : "=v"(r) : "v"(lo), "v"(hi));
    return r;
}
__device__ __forceinline__ u16 f2bf1(float f) {
    return (u16)((__float_as_uint(f) + 0x8000u) >> 16);
}

// Swizzled A-frag-order offset for a h [128x128] region: XOR (k>>3)&3 into
// the chunk index (readers apply chunk^quad) to spread the epilogue's
// column-wise u16 writes across more banks.
__device__ __forceinline__ int afoff_h(int m, int k) {
    int chunk = ((k >> 5) * 8 + (m >> 4)) * 64 + ((k >> 3) & 3) * 16 + (m & 15);
    chunk ^= (k >> 3) & 3;
    return chunk * 8 + (k & 7);
}

// channel/slot -> original mlp_in k index (reference ordering)
__device__ __forceinline__ int orig_k(int ch, int slot) {
    if (ch < 27) {
        if (slot == 0) return ch;
        if (slot <= 6) return 30 + ch * 6 + (slot - 1);     // sin(app)
        return 192 + ch * 6 + (slot - 7);                    // cos(app)
    } else {
        int c = ch - 27;
        if (slot == 0) return 27 + c;
        if (slot <= 6) return 354 + c * 6 + (slot - 1);      // sin(view)
        return 372 + c * 6 + (slot - 7);                     // cos(view)
    }
}

__device__ __forceinline__ float ldch(const float* ap, const float* vp, int c) {
    return (c < 27) ? ap[c] : vp[c - 27];
}

// build one channel-half of a frag-order X slice at a precomputed dst:
// slots [v, sin f0..5, cos f0..5, 0 x3] as two 16B chunks (dst, dst+128).
__device__ __forceinline__ void build_x(u16* dst, float v) {
    float rev = v * 0.15915494309189535f;
    rev -= floorf(rev);
    float s0 = __builtin_amdgcn_sinf(rev);
    float c0 = __builtin_amdgcn_cosf(rev);
    float s1 = 2.f * s0 * c0, c1 = c0 * c0 - s0 * s0;
    float s2 = 2.f * s1 * c1, c2 = c1 * c1 - s1 * s1;
    float s3 = 2.f * s2 * c2, c3 = c2 * c2 - s2 * s2;
    float s4 = 2.f * s3 * c3, c4 = c3 * c3 - s3 * s3;
    float s5 = 2.f * s4 * c4, c5 = c4 * c4 - s4 * s4;
    uint4 lo, hi;
    lo.x = pk(s0, v);  lo.y = pk(s2, s1);  lo.z = pk(s4, s3);  lo.w = pk(c0, s5);
    hi.x = pk(c2, c1); hi.y = pk(c4, c3);  hi.z = pk(0.f, c5); hi.w = 0u;
    *(uint4*)(dst)       = lo;
    *(uint4*)(dst + 128) = hi;
}

// W1 -> 15 slices, W2 -> 4 slices, W3 -> 4 mini B-frag slices (N padded 16)
__global__ __launch_bounds__(256) void prep_kernel(
    const float* __restrict__ W1, const float* __restrict__ W2,
    const float* __restrict__ W3, u16* __restrict__ ws)
{
    int idx = blockIdx.x * 256 + threadIdx.x;
    if (idx < 61440) {                               // W1r: [ks15][nt8][lane64][j8]
        int j = idx & 7, lane = (idx >> 3) & 63, nt = (idx >> 9) & 7, ks = idx >> 12;
        int q = lane >> 4, l15 = lane & 15;
        int klocal = q * 8 + j;                      // 0..31
        int ch = ks * 2 + (klocal >> 4);
        int slot = klocal & 15;
        int n = nt * 16 + l15;
        ws[idx] = (slot < 13) ? f2bf(W1[orig_k(ch, slot) * 128 + n]) : (u16)0;
    } else if (idx < 77824) {                        // W2r: [ks4][nt8][lane64][j8]
        int i2 = idx - 61440;
        int j = i2 & 7, lane = (i2 >> 3) & 63, nt = (i2 >> 9) & 7, ks = i2 >> 12;
        int k = ks * 32 + (lane >> 4) * 8 + j;
        int n = nt * 16 + (lane & 15);
        ws[idx] = f2bf(W2[k * 128 + n]);
    } else if (idx < 79872) {                        // W3r: [ks4][lane64][j8], N pad 16
        int i3 = idx - 77824;
        int j = i3 & 7, lane = (i3 >> 3) & 63, ks = i3 >> 9;
        int k = ks * 32 + (lane >> 4) * 8 + j;
        int n = lane & 15;
        ws[idx] = (n < 3) ? f2bf(W3[k * 3 + n]) : (u16)0;
    }
}

// Load one slice's 2 B-frags (wave's 32-col strip) into named registers.
#define LOADB2(N0, N1, s)                                                     \
    if ((s) < NSLICE) {                                                       \
        const u16* wp = wp0 + (s) * 4096;                                     \
        N0 = *(const bf16x8*)(wp);                                            \
        N1 = *(const bf16x8*)(wp + 512);                                      \
    }

// One X-sourced K-slice: 4 A ds_reads (64-row strip, split 2+2) + 8 MFMA.
// Loads slice s+2's B-frags (3-pair rotation P,Q,R).
#define BODYX(s, C0,C1, N0,N1)                                                \
  {                                                                           \
    LOADB2(N0, N1, (s)+2);                                                    \
    const u16* ab = pool + ((s)&7)*4096 + (wm*256 + lane)*8;                  \
    bf16x8 a0 = *(const bf16x8*)(ab);                                         \
    bf16x8 a1 = *(const bf16x8*)(ab + 512);                                   \
    __builtin_amdgcn_s_setprio(1);                                            \
    acc[0][0]=MF(a0,C0,acc[0][0]); acc[0][1]=MF(a0,C1,acc[0][1]);             \
    acc[1][0]=MF(a1,C0,acc[1][0]); acc[1][1]=MF(a1,C1,acc[1][1]);             \
    a0 = *(const bf16x8*)(ab + 1024);                                         \
    a1 = *(const bf16x8*)(ab + 1536);                                         \
    acc[2][0]=MF(a0,C0,acc[2][0]); acc[2][1]=MF(a0,C1,acc[2][1]);             \
    acc[3][0]=MF(a1,C0,acc[3][0]); acc[3][1]=MF(a1,C1,acc[3][1]);             \
    __builtin_amdgcn_s_setprio(0);                                            \
  }

// One h-sourced K-slice (GEMM2): A from swizzled h1 chunks (slots 0,1).
#define BODYH(s, C0,C1, N0,N1)                                                \
  {                                                                           \
    LOADB2(N0, N1, (s)+2);                                                    \
    int cb = ((((s)-15)*512) + wm*256 + lane) ^ quad;                         \
    bf16x8 a0 = *(const bf16x8*)(pool + cb*8);                                \
    bf16x8 a1 = *(const bf16x8*)(pool + (cb+64)*8);                           \
    __builtin_amdgcn_s_setprio(1);                                            \
    acc[0][0]=MF(a0,C0,acc[0][0]); acc[0][1]=MF(a0,C1,acc[0][1]);             \
    acc[1][0]=MF(a1,C0,acc[1][0]); acc[1][1]=MF(a1,C1,acc[1][1]);             \
    a0 = *(const bf16x8*)(pool + (cb+128)*8);                                 \
    a1 = *(const bf16x8*)(pool + (cb+192)*8);                                 \
    acc[2][0]=MF(a0,C0,acc[2][0]); acc[2][1]=MF(a0,C1,acc[2][1]);             \
    acc[3][0]=MF(a1,C0,acc[3][0]); acc[3][1]=MF(a1,C1,acc[3][1]);             \
    __builtin_amdgcn_s_setprio(0);                                            \
  }

// End of 2-group phase p: build groups 2p+2, 2p+3 into their slots, roll the
// 4-deep input prefetch (load groups 2p+6, 2p+7), single barrier.
#define GENDQ(p)                                                              \
  {                                                                           \
    if (8*(p)+8  + cl < 30)                                                   \
        build_x(pool + ((2*(p)+2)&3)*8192 + (cl>>1)*4096 + bxoff, pv_a);      \
    if (8*(p)+12 + cl < 30)                                                   \
        build_x(pool + ((2*(p)+3)&3)*8192 + (cl>>1)*4096 + bxoff, pv_b);      \
    pv_a = pv_c; pv_b = pv_d;                                                 \
    if (8*(p)+24 + cl < 30) pv_c = ldch(ap, vp, 8*(p)+24 + cl);               \
    if (8*(p)+28 + cl < 30) pv_d = ldch(ap, vp, 8*(p)+28 + cl);               \
    BAR();                                                                    \
  }

// 8 waves: wave (wm = wave>>2, wn = wave&3) owns a 64x32 output tile
// (round-3 shape: A-amp 4 via LDS, B-amp 2 via L1/L2 registers).
// 8 lgkm-only barriers per ray, no read-drain dependencies.
__global__ __launch_bounds__(512, 4) void render_kernel(
    const float* __restrict__ sigma_g, const float* __restrict__ app_g,
    const float* __restrict__ view_g,  const float* __restrict__ dists_g,
    const float* __restrict__ b1_g,    const float* __restrict__ b2_g,
    const float* __restrict__ b3_g,    const u16* __restrict__ ws,
    float* __restrict__ out_g)
{
    __shared__ __align__(16) u16 pool[POOLSZ];
    __shared__ __align__(16) float part[NS * 3];
    __shared__ float scanS;          // wave0 scan total broadcast
    __shared__ float sum2[6];        // per-wave final partials

    const int tid  = threadIdx.x;
    const int lane = tid & 63;
    const int wave = tid >> 6;       // 0..7
    const int l15  = lane & 15;
    const int quad = lane >> 4;
    const int wm   = wave >> 2;      // row half (64 rows)
    const int wn   = wave & 3;       // col quarter (32 cols)

    const int r  = blockIdx.x;
    const int rb = r * NS;
    const int row = tid & 127;       // X-build row (all 512 threads build)
    const int cl  = tid >> 7;        // X-build channel-local 0..3 (2 slices)
    const float* ap = app_g  + (rb + row) * 27;
    const float* vp = view_g + (rb + row) * 3;
    // hoisted per-thread build offset within a slice
    const int bxoff = (row >> 4) * 512 + (((cl & 1) * 32) + (row & 15)) * 8;

    // issue B loads for slices 0,1 ASAP (3-pair rotation P,Q,R)
    const u16* wp0 = ws + (wn * 128 + lane) * 8;
    bf16x8 bP0, bP1, bQ0, bQ1, bR0, bR1;
    LOADB2(bP0, bP1, 0);
    LOADB2(bQ0, bQ1, 1);

    // rolling input prefetch (4 resident: groups g..g+3's channel values)
    float pv_a = ldch(ap, vp, cl);           // g0
    float pv_b = ldch(ap, vp, 4 + cl);       // g1
    float pv_c = ldch(ap, vp, 8 + cl);       // g2
    float pv_d = ldch(ap, vp, 12 + cl);      // g3

    // ---- alpha + shuffle transmittance scan (waves 0,1) ----
    float alpha = 0.f, prod = 1.f, wr = 0.f;
    if (tid < NS) {
        float x  = sigma_g[rb + tid] - 10.f;
        float sp = (x > 20.f) ? x : log1pf(expf(x));
        alpha = 1.f - expf(-sp * dists_g[rb + tid] * 25.f);
        if (tid == NS - 1) alpha = 1.f;
        float tb = 1.f - alpha + 1e-10f;
        prod = tb;
        #pragma unroll
        for (int d = 1; d < 64; d <<= 1) {
            float v = __shfl_up(prod, d);
            if (lane >= d) prod *= v;
        }
        if (tid == 63) scanS = prod;
    }

    // ---- pre-build X groups 0,1 (slices 0..3) into slots 0,1 ----
    build_x(pool +        (cl >> 1) * 4096 + bxoff, pv_a);
    build_x(pool + 8192 + (cl >> 1) * 4096 + bxoff, pv_b);
    pv_a = pv_c; pv_b = pv_d;
    pv_c = ldch(ap, vp, 16 + cl);            // g4
    pv_d = ldch(ap, vp, 20 + cl);            // g5
    BAR();

    // finish weights: wr = alpha * T_exclusive
    if (tid < NS) {
        float prev = __shfl_up(prod, 1);
        float base = (lane == 0) ? 1.f : prev;
        float scale = (wave == 1) ? scanS : 1.f;
        wr = alpha * base * scale;
    }

    const f32x4 vzero = {0.f, 0.f, 0.f, 0.f};
    f32x4 acc[4][2];
    #pragma unroll
    for (int mt = 0; mt < 4; ++mt)
        #pragma unroll
        for (int nt = 0; nt < 2; ++nt) acc[mt][nt] = vzero;

    // ---- GEMM1: slices 0..14, 4-slice phases (pair s%3: 0=P 1=Q 2=R) ----
    BODYX(0,  bP0,bP1, bR0,bR1);
    BODYX(1,  bQ0,bQ1, bP0,bP1);
    BODYX(2,  bR0,bR1, bQ0,bQ1);
    BODYX(3,  bP0,bP1, bR0,bR1);  GENDQ(0);   // builds g2,g3 (slices 4..7)
    BODYX(4,  bQ0,bQ1, bP0,bP1);
    BODYX(5,  bR0,bR1, bQ0,bQ1);
    BODYX(6,  bP0,bP1, bR0,bR1);
    BODYX(7,  bQ0,bQ1, bP0,bP1);  GENDQ(1);   // builds g4,g5 (slices 8..11)
    BODYX(8,  bR0,bR1, bQ0,bQ1);
    BODYX(9,  bP0,bP1, bR0,bR1);
    BODYX(10, bQ0,bQ1, bP0,bP1);
    BODYX(11, bR0,bR1, bQ0,bQ1);  GENDQ(2);   // builds g6,g7 (slices 12..14)
    // b1 issued here so its latency hides under the last GEMM1 phase
    const float b1r0 = b1_g[wn * 32 + l15];
    const float b1r1 = b1_g[wn * 32 + 16 + l15];
    BODYX(12, bP0,bP1, bR0,bR1);
    BODYX(13, bQ0,bQ1, bP0,bP1);              // loads slice 15 -> P
    BODYX(14, bR0,bR1, bQ0,bQ1);              // loads slice 16 -> Q

    // ---- epilogue 1 (NO barrier needed): h1 -> slots 0,1; concurrent
    // slice-12..14 reads live in slots 2,3 (disjoint). ----
    #pragma unroll
    for (int mt = 0; mt < 4; ++mt)
        #pragma unroll
        for (int nt = 0; nt < 2; ++nt) {
            int col = wn * 32 + nt * 16 + l15;
            #pragma unroll
            for (int rr = 0; rr < 4; ++rr) {
                int rw = wm * 64 + mt * 16 + quad * 4 + rr;
                pool[afoff_h(rw, col)] =
                    f2bf1(fmaxf(acc[mt][nt][rr] + ((nt == 0) ? b1r0 : b1r1), 0.f));
            }
            acc[mt][nt] = vzero;          // reset for GEMM2
        }
    BAR();   // h1 visible to all waves AND slot-2,3 reads drained

    const float b2r0 = b2_g[wn * 32 + l15];
    const float b2r1 = b2_g[wn * 32 + 16 + l15];

    // ---- GEMM2: slices 15..18 (h1 @ W2), barrier-free run ----
    BODYH(15, bP0,bP1, bR0,bR1);              // loads slice 17 -> R
    BODYH(16, bQ0,bQ1, bP0,bP1);              // loads slice 18 -> P
    BODYH(17, bR0,bR1, bQ0,bQ1);
    BODYH(18, bP0,bP1, bR0,bR1);

    // ---- epilogue 2 (NO barrier needed): h2 -> slots 2,3; concurrent GEMM2
    // reads live in slots 0,1 (disjoint); old slot-2,3 readers drained above.
    #pragma unroll
    for (int mt = 0; mt < 4; ++mt)
        #pragma unroll
        for (int nt = 0; nt < 2; ++nt) {
            int col = wn * 32 + nt * 16 + l15;
            #pragma unroll
            for (int rr = 0; rr < 4; ++rr) {
                int rw = wm * 64 + mt * 16 + quad * 4 + rr;
                pool[OH2 + afoff_h(rw, col)] =
                    f2bf1(fmaxf(acc[mt][nt][rr] + ((nt == 0) ? b2r0 : b2r1), 0.f));
            }
        }
    BAR();   // h2 visible

    // ---- layer 3 via MFMA: rgb = sigmoid(h2 @ W3 + b3); wave = row-tile ----
    const u16* w3r = ws + 77824;
    const float b3v = (l15 < 3) ? b3_g[l15] : 0.f;
    f32x4 acc3 = vzero;
    #pragma unroll
    for (int ks = 0; ks < 4; ++ks) {
        bf16x8 w3f = *(const bf16x8*)(w3r + (ks * 64 + lane) * 8);
        int c = ((ks * 8 + wave) * 64 + lane) ^ quad;
        bf16x8 a3 = *(const bf16x8*)(pool + OH2 + c * 8);
        acc3 = MF(a3, w3f, acc3);
    }
    if (l15 < 3) {
        #pragma unroll
        for (int rr = 0; rr < 4; ++rr) {
            int rw = wave * 16 + quad * 4 + rr;
            float v = acc3[rr] + b3v;
            part[rw * 3 + l15] = 1.f / (1.f + expf(-v));
        }
    }
    BAR();

    // ---- weighted sum over samples ----
    if (tid < NS) {
        float v0 = wr * part[tid * 3 + 0];
        float v1 = wr * part[tid * 3 + 1];
        float v2 = wr * part[tid * 3 + 2];
        #pragma unroll
        for (int d = 1; d < 64; d <<= 1) {
            v0 += __shfl_xor(v0, d);
            v1 += __shfl_xor(v1, d);
            v2 += __shfl_xor(v2, d);
        }
        if (lane == 0) {
            sum2[wave * 3 + 0] = v0;
            sum2[wave * 3 + 1] = v1;
            sum2[wave * 3 + 2] = v2;
        }
    }
    BAR();
    if (tid == 0) {
        out_g[r * 3 + 0] = sum2[0] + sum2[3];
        out_g[r * 3 + 1] = sum2[1] + sum2[4];
        out_g[r * 3 + 2] = sum2[2] + sum2[5];
    }
}

extern "C" void kernel_launch(void* const* d_in, const int* in_sizes, int n_in,
                              void* d_out, int out_size, void* d_ws, size_t ws_size,
                              hipStream_t stream) {
    (void)in_sizes; (void)n_in; (void)out_size; (void)ws_size;
    const float* sigma = (const float*)d_in[0];
    const float* app   = (const float*)d_in[1];
    const float* view  = (const float*)d_in[2];
    const float* dists = (const float*)d_in[3];
    const float* W1    = (const float*)d_in[4];
    const float* b1    = (const float*)d_in[5];
    const float* W2    = (const float*)d_in[6];
    const float* b2    = (const float*)d_in[7];
    const float* W3    = (const float*)d_in[8];
    const float* b3    = (const float*)d_in[9];
    float* out = (float*)d_out;

    u16* ws = (u16*)d_ws;   // 61440 (W1r) + 16384 (W2r) + 2048 (W3r) u16 = 159744 B

    prep_kernel<<<312, 256, 0, stream>>>(W1, W2, W3, ws);
    render_kernel<<<NBLOCKS, 512, 0, stream>>>(sigma, app, view, dists,
                                               b1, b2, b3, ws, out);
}